// Round 10
// baseline (12194.636 us; speedup 1.0000x reference)
//
#include <hip/hip_runtime.h>
#include <hip/hip_fp16.h>

// LSTM B=8192 S=1024 H=256 — round 10: cross-set pipeline inside r7's phase.
// r8/r9 proved phase = VALU_time + MFMA_time (in-phase dependency serializes
// the pipes). Fix: phase (S,t) = MFMA K-loop for set S  INTERLEAVED with
// elementwise+publish of set S^1's gates from the previous phase (independent
// regs). Per-wave flags + mid-phase s_waitcnt vmcnt(0) let the publish go out
// without a barrier; peer DMA (4 KB, own half via ds_write) is issued before
// the back-half MFMAs so its latency hides under them. Gate math: 8 trans/cell
// (single-rcp forms). w0/bias in LDS as f32. 256 blocks x 512 thr, 1 block/CU,
// pairs {B,B^8}; wfrag 128 regs STATIC-indexed (r3/r4 trap avoided).

typedef _Float16 f16x8 __attribute__((ext_vector_type(8)));
typedef float f32x4 __attribute__((ext_vector_type(4)));
typedef unsigned int u32;
typedef unsigned short u16;

#define WINT_OFF 0u
#define W0B_OFF  524288u
#define FLAG_OFF 528384u   // int[256 blocks][2 sets][16] = 32 KB (per-wave flags)
#define PUB_OFF  1048576u  // u16[(set*2+par)*128+pair][2 half][4096] = 8 MB

static __device__ __forceinline__ float fast_exp2(float x) {
#if __has_builtin(__builtin_amdgcn_exp2f)
  return __builtin_amdgcn_exp2f(x);
#else
  return exp2f(x);
#endif
}
static __device__ __forceinline__ float fast_rcp(float x) {
#if __has_builtin(__builtin_amdgcn_rcpf)
  return __builtin_amdgcn_rcpf(x);
#else
  return 1.0f / x;
#endif
}
static __device__ __forceinline__ u16 f16b(float f) {
  union { _Float16 h; u16 u; } cv; cv.h = (_Float16)f; return cv.u;
}
static __device__ __forceinline__ float h2f(u16 u) {
  union { u16 u; _Float16 h; } cv; cv.u = u; return (float)cv.h;
}
static __device__ __forceinline__ u16* pub_base(u16* pub, int set, int par,
                                                int pid, int half) {
  return pub + ((size_t)(((set * 2 + par) * 128 + pid) * 2 + half) << 12);
}

// Wint[n][k], n = g*256 + j; w0b[n] = packed fp16 {w0, bias}.
__global__ void lstm_prep(const float* __restrict__ Wf, const float* __restrict__ Wi,
                          const float* __restrict__ Wc, const float* __restrict__ Wo,
                          const float* __restrict__ bf_, const float* __restrict__ bi_,
                          const float* __restrict__ bc_, const float* __restrict__ bo_,
                          u16* __restrict__ Wint, u32* __restrict__ w0b) {
  int n = blockIdx.x;       // 0..1023
  int k = threadIdx.x;      // 0..255
  int g = n >> 8, j = n & 255;
  const float* Ws = (g == 0) ? Wf : (g == 1) ? Wi : (g == 2) ? Wc : Wo;
  Wint[n * 256 + k] = f16b(Ws[j * 257 + 1 + k]);
  if (k == 0) {
    const float* bs = (g == 0) ? bf_ : (g == 1) ? bi_ : (g == 2) ? bc_ : bo_;
    w0b[n] = (u32)f16b(Ws[j * 257]) | ((u32)f16b(bs[j]) << 16);
  }
}

// Zero parity-0 pub of both sets (h_0 = 0), flags, out = bout.
__global__ void lstm_zero(uint4* __restrict__ pub4, uint4* __restrict__ flags4,
                          float* __restrict__ out, const float* __restrict__ bout) {
  int idx = blockIdx.x * 256 + threadIdx.x;
  uint4 z = uint4{0, 0, 0, 0};
  if (idx < 131072) pub4[idx] = z;                 // slot (s0,p0): 2 MB
  else if (idx < 262144) pub4[idx + 131072] = z;   // slot (s1,p0): 2 MB
  else if (idx < 264192) flags4[idx - 262144] = z; // 32 KB flags
  else { int o = idx - 264192; if (o < 8192) out[o] = bout[0]; }
}

__global__ __launch_bounds__(512, 2) void lstm_main(
    const u16* __restrict__ Wint, const u32* __restrict__ w0b,
    const float* __restrict__ x, const float* __restrict__ Wout,
    float* __restrict__ out, u16* __restrict__ pub, int* __restrict__ flags) {

  __shared__ __align__(16) u16 stg[2][2][4096];  // [set][0=own k-half,1=peer][32x128]
  __shared__ __align__(16) float lw0f[512], lbsf[512];

  const int tid  = threadIdx.x;
  const int wv   = tid >> 6;
  const int lane = tid & 63;
  const int l15  = lane & 15;
  const int quad = lane >> 4;
  const int B    = blockIdx.x;
  const int mi   = (B >> 3) & 1;
  const int peer = B ^ 8;
  const int pid  = (B & 7) | ((B >> 4) << 3);   // pair 0..127
  const int rows0 = pid * 64;
  const int j0w  = mi * 128 + wv * 16;          // wave's global j base

  // ---- one-time: W A-fragments (128 regs, STATIC reg indices) ----
  f16x8 wfrag[4][8];
#pragma unroll
  for (int g = 0; g < 4; ++g)
#pragma unroll
    for (int hm = 0; hm < 2; ++hm)
#pragma unroll
      for (int ktl = 0; ktl < 4; ++ktl) {
        int kbase = (hm == 0 ? mi : 1 - mi) * 128 + ktl * 32;  // addr only
        wfrag[g][hm * 4 + ktl] = *(const f16x8*)(Wint +
            (size_t)(g * 256 + j0w + l15) * 256 + kbase + quad * 8);
      }
  // w0/bias unpacked to f32 in LDS (own j-half: [g][lj])
  {
    u32 pk = w0b[(tid >> 7) * 256 + mi * 128 + (tid & 127)];
    lw0f[tid] = h2f((u16)pk);
    lbsf[tid] = h2f((u16)(pk >> 16));
  }
  // zero stg (h_0 images): 32 KB
#pragma unroll
  for (int i = 0; i < 4; ++i) ((uint4*)stg)[tid + i * 512] = uint4{0, 0, 0, 0};

  float cst[2][2][4];   // [set][bt][r]: cell (b = bt*16+l15, j = j0w+quad*4+r)
#pragma unroll
  for (int s = 0; s < 2; ++s)
#pragma unroll
    for (int bt = 0; bt < 2; ++bt)
#pragma unroll
      for (int r = 0; r < 4; ++r) cst[s][bt][r] = 0.0f;

  const float* xq = x + (size_t)rows0 * 1024;
  float xcur[2][2];
#pragma unroll
  for (int s = 0; s < 2; ++s)
#pragma unroll
    for (int bt = 0; bt < 2; ++bt)
      xcur[s][bt] = xq[(size_t)(s * 32 + bt * 16 + l15) * 1024];

  f32x4 acc0[4][2], acc1[4][2];

  __syncthreads();

// PHASE(S, ACC, ACCP, FSTEP, DO_EW):
// MFMA K-loop set S (stg[S], filled last phase) -> ACC; elementwise+publish of
// set S^1 from ACCP (prev phase) -> h_{S^1}(FSTEP); mid-phase per-wave flag;
// poll peer + DMA peer half before back-half MFMAs (latency hidden).
#define PHASE(S, ACC, ACCP, FSTEP, DO_EW)                                         \
  {                                                                               \
    const int sd_ = 1 - (S);                                                      \
    /* acc init = x*w0 + bias (LDS f32) */                                        \
    _Pragma("unroll")                                                             \
    for (int g = 0; g < 4; ++g) {                                                 \
      f32x4 wv4_ = *(const f32x4*)&lw0f[g * 128 + wv * 16 + quad * 4];            \
      f32x4 bv4_ = *(const f32x4*)&lbsf[g * 128 + wv * 16 + quad * 4];            \
      _Pragma("unroll")                                                           \
      for (int r = 0; r < 4; ++r) {                                               \
        ACC[g][0][r] = xcur[S][0] * wv4_[r] + bv4_[r];                            \
        ACC[g][1][r] = xcur[S][1] * wv4_[r] + bv4_[r];                            \
      }                                                                           \
    }                                                                             \
    /* front MFMAs: ks 0-1 (own k-half) */                                        \
    _Pragma("unroll")                                                             \
    for (int ks = 0; ks < 2; ++ks) {                                              \
      const u16* bs_ = &stg[S][0][0];                                             \
      int cp_ = (ks * 4 + quad) ^ l15;                                            \
      f16x8 ba_ = *(const f16x8*)(bs_ + l15 * 128 + cp_ * 8);                     \
      f16x8 bb_ = *(const f16x8*)(bs_ + (16 + l15) * 128 + cp_ * 8);              \
      _Pragma("unroll")                                                           \
      for (int g = 0; g < 4; ++g) {                                               \
        ACC[g][0] = __builtin_amdgcn_mfma_f32_16x16x32_f16(wfrag[g][ks], ba_,     \
                                                           ACC[g][0], 0, 0, 0);   \
        ACC[g][1] = __builtin_amdgcn_mfma_f32_16x16x32_f16(wfrag[g][ks], bb_,     \
                                                           ACC[g][1], 0, 0, 0);   \
      }                                                                           \
    }                                                                             \
    /* elementwise set sd_ (prev acc) + publish global + ds_write own half */     \
    if (DO_EW) {                                                                  \
      u16* pb_ = pub_base(pub, sd_, (FSTEP) & 1, pid, mi);                        \
      u16* ls_ = &stg[sd_][0][0];                                                 \
      _Pragma("unroll")                                                           \
      for (int bt = 0; bt < 2; ++bt) {                                            \
        int brow_ = bt * 16 + l15;                                                \
        float h4_[4];                                                             \
        _Pragma("unroll")                                                         \
        for (int r = 0; r < 4; ++r) {                                             \
          float fg_ = ACCP[0][bt][r], ig_ = ACCP[1][bt][r];                       \
          float cg_ = ACCP[2][bt][r], og_ = ACCP[3][bt][r];                       \
          float ef_ = fast_exp2(-1.44269504f * fg_);                              \
          float ei_ = fast_exp2(-1.44269504f * ig_);                              \
          float eg_ = fast_exp2(2.88539008f * cg_);                               \
          float eo_ = fast_exp2(-1.44269504f * og_);                              \
          float c_ = cst[sd_][bt][r] * fast_rcp(1.0f + ef_) +                     \
                     (eg_ - 1.0f) * fast_rcp((1.0f + ei_) * (eg_ + 1.0f));        \
          cst[sd_][bt][r] = c_;                                                   \
          float ec_ = fast_exp2(2.88539008f * c_);                                \
          h4_[r] = (ec_ - 1.0f) * fast_rcp((1.0f + eo_) * (ec_ + 1.0f));          \
        }                                                                         \
        u32 lo_ = (u32)f16b(h4_[0]) | ((u32)f16b(h4_[1]) << 16);                  \
        u32 hi_ = (u32)f16b(h4_[2]) | ((u32)f16b(h4_[3]) << 16);                  \
        int off_ = brow_ * 128 + ((wv * 2 + (quad >> 1)) ^ l15) * 8 +             \
                   (quad & 1) * 4;                                                \
        *(uint2*)(pb_ + off_) = uint2{lo_, hi_};                                  \
        *(uint2*)(ls_ + off_) = uint2{lo_, hi_};                                  \
      }                                                                           \
    }                                                                             \
    /* per-wave flag after own stores drain (no barrier needed) */                \
    __builtin_amdgcn_s_waitcnt(0x0f70); /* vmcnt(0) only */                       \
    if ((DO_EW) && lane == 0)                                                     \
      __hip_atomic_store(flags + ((B) * 2 + sd_) * 16 + wv, (FSTEP),              \
                         __ATOMIC_RELAXED, __HIP_MEMORY_SCOPE_AGENT);             \
    /* poll peer's 8 wave-flags + DMA peer half (hidden under back MFMAs) */      \
    {                                                                             \
      const int* pfl_ = flags + (peer * 2 + sd_) * 16;                            \
      for (;;) {                                                                  \
        int mn_ = 0x7fffffff;                                                     \
        _Pragma("unroll")                                                         \
        for (int d = 0; d < 8; ++d) {                                             \
          int v_ = __hip_atomic_load(pfl_ + d, __ATOMIC_RELAXED,                  \
                                     __HIP_MEMORY_SCOPE_AGENT);                   \
          mn_ = mn_ < v_ ? mn_ : v_;                                              \
        }                                                                         \
        if (mn_ >= (FSTEP)) break;                                                \
        __builtin_amdgcn_s_sleep(1);                                              \
      }                                                                           \
      const u16* src_ = pub_base(pub, sd_, (FSTEP) & 1, pid, 1 - mi);             \
      __builtin_amdgcn_global_load_lds(                                           \
          (const __attribute__((address_space(1))) u32*)(src_ + wv * 512 +        \
                                                         lane * 8),               \
          (__attribute__((address_space(3))) u32*)(&stg[sd_][1][wv * 512]),       \
          16, 0, 0);                                                              \
    }                                                                             \
    /* back MFMAs: ks 2-7 */                                                      \
    _Pragma("unroll")                                                             \
    for (int ks = 2; ks < 8; ++ks) {                                              \
      const u16* bs_ = &stg[S][ks >> 2][0];                                       \
      int cp_ = ((ks & 3) * 4 + quad) ^ l15;                                      \
      f16x8 ba_ = *(const f16x8*)(bs_ + l15 * 128 + cp_ * 8);                     \
      f16x8 bb_ = *(const f16x8*)(bs_ + (16 + l15) * 128 + cp_ * 8);              \
      _Pragma("unroll")                                                           \
      for (int g = 0; g < 4; ++g) {                                               \
        ACC[g][0] = __builtin_amdgcn_mfma_f32_16x16x32_f16(wfrag[g][ks], ba_,     \
                                                           ACC[g][0], 0, 0, 0);   \
        ACC[g][1] = __builtin_amdgcn_mfma_f32_16x16x32_f16(wfrag[g][ks], bb_,     \
                                                           ACC[g][1], 0, 0, 0);   \
      }                                                                           \
    }                                                                             \
    /* x prefetch for (S, t+1) */                                                 \
    xcur[S][0] = xq[(size_t)((S) * 32 + l15) * 1024 + ((t + 1) & 1023)];          \
    xcur[S][1] = xq[(size_t)((S) * 32 + 16 + l15) * 1024 + ((t + 1) & 1023)];     \
    __syncthreads(); /* drains DMA + ds_write for next phase */                   \
  }

#pragma unroll 1
  for (int t = 0; t < 1024; ++t) {
    PHASE(0, acc0, acc1, t, (t > 0));
    PHASE(1, acc1, acc0, (t + 1), 1);
  }
#undef PHASE

  // ---- epilogue: elementwise of set1 gates(1023) -> h_B(1024) -> stg[1][0] ----
  {
    u16* ls = &stg[1][0][0];
#pragma unroll
    for (int bt = 0; bt < 2; ++bt) {
      int brow = bt * 16 + l15;
      float h4[4];
#pragma unroll
      for (int r = 0; r < 4; ++r) {
        float fg = acc1[0][bt][r], ig = acc1[1][bt][r];
        float cg = acc1[2][bt][r], og = acc1[3][bt][r];
        float ef = fast_exp2(-1.44269504f * fg);
        float ei = fast_exp2(-1.44269504f * ig);
        float eg = fast_exp2(2.88539008f * cg);
        float eo = fast_exp2(-1.44269504f * og);
        float c_ = cst[1][bt][r] * fast_rcp(1.0f + ef) +
                   (eg - 1.0f) * fast_rcp((1.0f + ei) * (eg + 1.0f));
        float ec = fast_exp2(2.88539008f * c_);
        h4[r] = (ec - 1.0f) * fast_rcp((1.0f + eo) * (ec + 1.0f));
      }
      u32 lo = (u32)f16b(h4[0]) | ((u32)f16b(h4[1]) << 16);
      u32 hi = (u32)f16b(h4[2]) | ((u32)f16b(h4[3]) << 16);
      int off = brow * 128 + ((wv * 2 + (quad >> 1)) ^ l15) * 8 + (quad & 1) * 4;
      *(uint2*)(ls + off) = uint2{lo, hi};
    }
  }
  __syncthreads();

  // ---- out[b] += (own j-half of h_1024) . Wout  (out pre-set to bout) ----
  // stg[0][0] = h_A(1024) (ds_written at P(1,1023)); stg[1][0] = h_B(1024).
  if (tid < 64) {
    int s = tid >> 5, b = tid & 31;
    const u16* img = &stg[s][0][0];
    float a = 0.0f;
#pragma unroll
    for (int lc = 0; lc < 16; ++lc) {
      f16x8 hv = *(const f16x8*)(img + b * 128 + ((lc ^ (b & 15)) * 8));
#pragma unroll
      for (int e = 0; e < 8; ++e) a += (float)hv[e] * Wout[mi * 128 + lc * 8 + e];
    }
    atomicAdd(&out[rows0 + s * 32 + b], a);
  }
}

extern "C" void kernel_launch(void* const* d_in, const int* in_sizes, int n_in,
                              void* d_out, int out_size, void* d_ws, size_t ws_size,
                              hipStream_t stream) {
  const float* x    = (const float*)d_in[0];
  const float* Wf   = (const float*)d_in[1];
  const float* bf_  = (const float*)d_in[2];
  const float* Wi   = (const float*)d_in[3];
  const float* bi_  = (const float*)d_in[4];
  const float* Wc   = (const float*)d_in[5];
  const float* bc_  = (const float*)d_in[6];
  const float* Wo   = (const float*)d_in[7];
  const float* bo_  = (const float*)d_in[8];
  const float* Wout = (const float*)d_in[9];
  const float* bout = (const float*)d_in[10];

  u16* Wint  = (u16*)((char*)d_ws + WINT_OFF);
  u32* w0b   = (u32*)((char*)d_ws + W0B_OFF);
  int* flags = (int*)((char*)d_ws + FLAG_OFF);
  u16* pub   = (u16*)((char*)d_ws + PUB_OFF);

  lstm_prep<<<1024, 256, 0, stream>>>(Wf, Wi, Wc, Wo, bf_, bi_, bc_, bo_, Wint, w0b);
  lstm_zero<<<1064, 256, 0, stream>>>((uint4*)pub, (uint4*)flags, (float*)d_out, bout);
  lstm_main<<<256, 512, 0, stream>>>(Wint, w0b, x, Wout, (float*)d_out, pub, flags);
}

// Round 11
// 5437.211 us; speedup vs baseline: 2.2428x; 2.2428x over previous
//
#include <hip/hip_runtime.h>
#include <hip/hip_fp16.h>

// LSTM B=8192 S=1024 H=256 — round 11: 4-set rotation.
// r8 proved phase = VALU + MFMA serialized (elementwise depends on same-phase
// K-loop); r10 proved cross-set pipelining dies if the peer link has no slack.
// This round: pairs {B,B^8} share 64 rows = 4 sets of 16. Phase(S,t):
//   MFMA set S (stg[S], filled >=2 phases ago)   } independent streams,
//   elementwise+publish set P=S-1 (prev phase)   } interleaved in one wave
//   poll+DMA set D=S+2 (image published ONE FULL phase ago — r7 slack)
//   one barrier; flag after barrier (publish drained).
// 256 blocks x 512 thr, 1 block/CU. wfrag 128 regs STATIC-indexed; 4-bit XOR
// chunk swizzle (r7's zero-conflict scheme); 8 trans/cell gate math.

typedef _Float16 f16x8 __attribute__((ext_vector_type(8)));
typedef float f32x4 __attribute__((ext_vector_type(4)));
typedef unsigned int u32;
typedef unsigned short u16;

#define WINT_OFF 0u
#define W0B_OFF  524288u
#define FLAG_OFF 528384u   // int[256 blocks][4 sets][16] = 64 KB
#define PUB_OFF  1048576u  // u16[set4][par2][pair128][half2][2048] = 8 MB

static __device__ __forceinline__ float fast_exp2(float x) {
#if __has_builtin(__builtin_amdgcn_exp2f)
  return __builtin_amdgcn_exp2f(x);
#else
  return exp2f(x);
#endif
}
static __device__ __forceinline__ float fast_rcp(float x) {
#if __has_builtin(__builtin_amdgcn_rcpf)
  return __builtin_amdgcn_rcpf(x);
#else
  return 1.0f / x;
#endif
}
static __device__ __forceinline__ u16 f16b(float f) {
  union { _Float16 h; u16 u; } cv; cv.h = (_Float16)f; return cv.u;
}
static __device__ __forceinline__ float h2f(u16 u) {
  union { u16 u; _Float16 h; } cv; cv.u = u; return (float)cv.h;
}

// Wint[n][k], n = g*256 + j; w0b[n] = packed fp16 {w0, bias}.
__global__ void lstm_prep(const float* __restrict__ Wf, const float* __restrict__ Wi,
                          const float* __restrict__ Wc, const float* __restrict__ Wo,
                          const float* __restrict__ bf_, const float* __restrict__ bi_,
                          const float* __restrict__ bc_, const float* __restrict__ bo_,
                          u16* __restrict__ Wint, u32* __restrict__ w0b) {
  int n = blockIdx.x;       // 0..1023
  int k = threadIdx.x;      // 0..255
  int g = n >> 8, j = n & 255;
  const float* Ws = (g == 0) ? Wf : (g == 1) ? Wi : (g == 2) ? Wc : Wo;
  Wint[n * 256 + k] = f16b(Ws[j * 257 + 1 + k]);
  if (k == 0) {
    const float* bs = (g == 0) ? bf_ : (g == 1) ? bi_ : (g == 2) ? bc_ : bo_;
    w0b[n] = (u32)f16b(Ws[j * 257]) | ((u32)f16b(bs[j]) << 16);
  }
}

// Zero parity-0 pub of all 4 sets (h_0 = 0), flags (64 KB), out = bout.
// Per (set,parity) image block = 128 pair x 2 half x 2048 u16 = 65536 uint4.
__global__ void lstm_zero(uint4* __restrict__ pub4, uint4* __restrict__ flags4,
                          float* __restrict__ out, const float* __restrict__ bout) {
  int idx = blockIdx.x * 256 + threadIdx.x;
  uint4 z = uint4{0, 0, 0, 0};
  if (idx < 262144) {
    int s = idx >> 16, off = idx & 65535;
    pub4[(size_t)s * 131072 + off] = z;        // parity-0 image of set s
  } else if (idx < 266240) flags4[idx - 262144] = z;
  else { int o = idx - 266240; if (o < 8192) out[o] = bout[0]; }
}

__global__ __launch_bounds__(512, 2) void lstm_main(
    const u16* __restrict__ Wint, const u32* __restrict__ w0b,
    const float* __restrict__ x, const float* __restrict__ Wout,
    float* __restrict__ out, u16* __restrict__ pub, int* __restrict__ flags) {

  __shared__ __align__(16) u16 stg[4][2][2048];  // [set][0=own j-half,1=peer][16x128]
  __shared__ __align__(16) float lw0f[512], lbsf[512];

  const int tid  = threadIdx.x;
  const int wv   = tid >> 6;
  const int lane = tid & 63;
  const int l15  = lane & 15;
  const int quad = lane >> 4;
  const int B    = blockIdx.x;
  const int mi   = (B >> 3) & 1;
  const int peer = B ^ 8;
  const int pid  = (B & 7) | ((B >> 4) << 3);   // pair 0..127
  const int rows0 = pid * 64;
  const int j0w  = mi * 128 + wv * 16;          // wave's global j base

  // ---- one-time: W A-fragments (128 regs, STATIC reg indices; mi addr-only) ----
  f16x8 wfrag[4][8];
#pragma unroll
  for (int g = 0; g < 4; ++g)
#pragma unroll
    for (int hm = 0; hm < 2; ++hm)
#pragma unroll
      for (int kt = 0; kt < 4; ++kt) {
        int kbase = (hm == 0 ? mi : 1 - mi) * 128 + kt * 32;
        wfrag[g][hm * 4 + kt] = *(const f16x8*)(Wint +
            (size_t)(g * 256 + j0w + l15) * 256 + kbase + quad * 8);
      }
  { // w0/bias unpacked to f32 in LDS (own j-half)
    u32 pk = w0b[(tid >> 7) * 256 + mi * 128 + (tid & 127)];
    lw0f[tid] = h2f((u16)pk);
    lbsf[tid] = h2f((u16)(pk >> 16));
  }
  // zero stg (h_0 images): 4 sets x 2 half x 2048 u16 = 2048 uint4
#pragma unroll
  for (int i = 0; i < 4; ++i) ((uint4*)stg)[tid + i * 512] = uint4{0, 0, 0, 0};

  float cst[4][4];     // [set][r]: cell (b = l15, j = j0w + quad*4 + r)
#pragma unroll
  for (int s = 0; s < 4; ++s)
#pragma unroll
    for (int r = 0; r < 4; ++r) cst[s][r] = 0.0f;

  const float* xq = x + (size_t)rows0 * 1024;
  float xcur[4];
#pragma unroll
  for (int s = 0; s < 4; ++s) xcur[s] = xq[(size_t)(s * 16 + l15) * 1024];

  int* const myfl = flags + B * 64;        // [set][16]
  const int* const pefl = flags + peer * 64;

  f32x4 accA[4], accB[4];

  __syncthreads();

// PHASE(S, P, D, ACCW, ACCR, TP, TD, DO_EW):
// MFMA set S -> ACCW; elementwise set P from ACCR -> h_P(TP), publish+ds_write;
// poll peer flag[D] >= TD (set after peer's previous-phase barrier) + DMA peer
// half of h_D(TD) into stg[D][1] (consumed 2 phases later); 1 barrier; flag.
#define PHASE(S, P, D, ACCW, ACCR, TP, TD, DO_EW)                                \
  {                                                                              \
    /* front B-frags (own k-half) */                                             \
    f16x8 bb0[4];                                                                \
    _Pragma("unroll")                                                            \
    for (int kt = 0; kt < 4; ++kt) {                                             \
      int cp = (kt * 4 + quad) ^ l15;                                            \
      bb0[kt] = *(const f16x8*)(&stg[S][0][0] + l15 * 128 + cp * 8);             \
    }                                                                            \
    /* acc init = x*w0 + bias */                                                 \
    _Pragma("unroll")                                                            \
    for (int g = 0; g < 4; ++g) {                                                \
      f32x4 w4 = *(const f32x4*)&lw0f[g * 128 + wv * 16 + quad * 4];             \
      f32x4 b4 = *(const f32x4*)&lbsf[g * 128 + wv * 16 + quad * 4];             \
      _Pragma("unroll")                                                          \
      for (int r = 0; r < 4; ++r) ACCW[g][r] = xcur[S] * w4[r] + b4[r];          \
    }                                                                            \
    /* front MFMAs (slots 0-3) — overlaps the elementwise below */               \
    _Pragma("unroll")                                                            \
    for (int kt = 0; kt < 4; ++kt)                                               \
      _Pragma("unroll")                                                          \
      for (int g = 0; g < 4; ++g)                                                \
        ACCW[g] = __builtin_amdgcn_mfma_f32_16x16x32_f16(wfrag[g][kt], bb0[kt],  \
                                                         ACCW[g], 0, 0, 0);      \
    /* elementwise set P (prev-phase gates; independent of ACCW stream) */       \
    u32 lo_ = 0, hi_ = 0;                                                        \
    if (DO_EW) {                                                                 \
      float h4[4];                                                               \
      _Pragma("unroll")                                                          \
      for (int r = 0; r < 4; ++r) {                                              \
        float fg = ACCR[0][r], ig = ACCR[1][r];                                  \
        float cg = ACCR[2][r], og = ACCR[3][r];                                  \
        float ef = fast_exp2(-1.44269504f * fg);                                 \
        float ei = fast_exp2(-1.44269504f * ig);                                 \
        float eg = fast_exp2(2.88539008f * cg);                                  \
        float eo = fast_exp2(-1.44269504f * og);                                 \
        float c_ = cst[P][r] * fast_rcp(1.0f + ef) +                             \
                   (eg - 1.0f) * fast_rcp((1.0f + ei) * (eg + 1.0f));            \
        cst[P][r] = c_;                                                          \
        float ec = fast_exp2(2.88539008f * c_);                                  \
        h4[r] = (ec - 1.0f) * fast_rcp((1.0f + eo) * (ec + 1.0f));               \
      }                                                                          \
      lo_ = (u32)f16b(h4[0]) | ((u32)f16b(h4[1]) << 16);                         \
      hi_ = (u32)f16b(h4[2]) | ((u32)f16b(h4[3]) << 16);                         \
    }                                                                            \
    /* poll (1-phase-old flag) + DMA peer half of h_D(TD); wv<4 only */          \
    if (wv < 4) {                                                                \
      while (__hip_atomic_load(pefl + (D) * 16, __ATOMIC_RELAXED,                \
                               __HIP_MEMORY_SCOPE_AGENT) < (TD))                 \
        __builtin_amdgcn_s_sleep(1);                                             \
      const u16* src = pub + ((size_t)(((((D) * 2 + ((TD) & 1)) * 128 + pid))    \
                              * 2 + (1 - mi)) << 11) + (wv * 64 + lane) * 8;     \
      __builtin_amdgcn_global_load_lds(                                          \
          (const __attribute__((address_space(1))) u32*)src,                     \
          (__attribute__((address_space(3))) u32*)(&stg[D][1][wv * 512]),        \
          16, 0, 0);                                                             \
    }                                                                            \
    /* back B-frags (peer k-half) + MFMAs (slots 4-7) */                         \
    f16x8 bb1[4];                                                                \
    _Pragma("unroll")                                                            \
    for (int kt = 0; kt < 4; ++kt) {                                             \
      int cp = (kt * 4 + quad) ^ l15;                                            \
      bb1[kt] = *(const f16x8*)(&stg[S][1][0] + l15 * 128 + cp * 8);             \
    }                                                                            \
    _Pragma("unroll")                                                            \
    for (int kt = 0; kt < 4; ++kt)                                               \
      _Pragma("unroll")                                                          \
      for (int g = 0; g < 4; ++g)                                                \
        ACCW[g] = __builtin_amdgcn_mfma_f32_16x16x32_f16(wfrag[g][4 + kt],       \
                                                         bb1[kt], ACCW[g],       \
                                                         0, 0, 0);               \
    /* publish h_P own half (global, parity TP&1) + ds_write into stg[P][0] */   \
    if (DO_EW) {                                                                 \
      int cx = (wv * 2 + (quad >> 1)) ^ l15;                                     \
      int off = l15 * 128 + cx * 8 + (quad & 1) * 4;                             \
      u16* pb = pub + ((size_t)(((((P) * 2 + ((TP) & 1)) * 128 + pid))           \
                       * 2 + mi) << 11);                                         \
      *(uint2*)(pb + off) = uint2{lo_, hi_};                                     \
      *(uint2*)(&stg[P][0][0] + off) = uint2{lo_, hi_};                          \
    }                                                                            \
    /* x prefetch for (S, t+1) */                                                \
    xcur[S] = xq[(size_t)((S) * 16 + l15) * 1024 + ((t + 1) & 1023)];            \
    __syncthreads();  /* drains publish + DMA + x before anyone proceeds */      \
    if ((DO_EW) && tid == 0)                                                     \
      __hip_atomic_store(myfl + (P) * 16, (TP), __ATOMIC_RELAXED,                \
                         __HIP_MEMORY_SCOPE_AGENT);                              \
  }

#pragma unroll 1
  for (int t = 0; t < 1024; ++t) {
    PHASE(0, 3, 2, accA, accB, t,     t,     (t > 0));
    PHASE(1, 0, 3, accB, accA, t + 1, t,     true);
    PHASE(2, 1, 0, accA, accB, t + 1, t + 1, true);
    PHASE(3, 2, 1, accB, accA, t + 1, t + 1, true);
  }
#undef PHASE

  // ---- epilogue: elementwise set3 gates(1023) -> h_3(1024) -> stg[3][0] ----
  {
    float h4[4];
#pragma unroll
    for (int r = 0; r < 4; ++r) {
      float fg = accB[0][r], ig = accB[1][r];
      float cg = accB[2][r], og = accB[3][r];
      float ef = fast_exp2(-1.44269504f * fg);
      float ei = fast_exp2(-1.44269504f * ig);
      float eg = fast_exp2(2.88539008f * cg);
      float eo = fast_exp2(-1.44269504f * og);
      float c_ = cst[3][r] * fast_rcp(1.0f + ef) +
                 (eg - 1.0f) * fast_rcp((1.0f + ei) * (eg + 1.0f));
      float ec = fast_exp2(2.88539008f * c_);
      h4[r] = (ec - 1.0f) * fast_rcp((1.0f + eo) * (ec + 1.0f));
    }
    u32 lo = (u32)f16b(h4[0]) | ((u32)f16b(h4[1]) << 16);
    u32 hi = (u32)f16b(h4[2]) | ((u32)f16b(h4[3]) << 16);
    int cx = (wv * 2 + (quad >> 1)) ^ l15;
    int off = l15 * 128 + cx * 8 + (quad & 1) * 4;
    *(uint2*)(&stg[3][0][0] + off) = uint2{lo, hi};
  }
  __syncthreads();

  // ---- out[b] += (own j-half of h_set(1024)) . Wout  (out pre-set to bout) ----
  // stg[s][0] holds h_s(1024) own half (ds_written in phases (s+1, 1023) / epilogue).
  if (tid < 64) {
    int s = tid >> 4, brow = tid & 15;
    const u16* img = &stg[s][0][0];
    float a = 0.0f;
#pragma unroll
    for (int lc = 0; lc < 16; ++lc) {
      f16x8 hv = *(const f16x8*)(img + brow * 128 + ((lc ^ brow) * 8));
#pragma unroll
      for (int e = 0; e < 8; ++e) a += (float)hv[e] * Wout[mi * 128 + lc * 8 + e];
    }
    atomicAdd(&out[rows0 + s * 16 + brow], a);
  }
}

extern "C" void kernel_launch(void* const* d_in, const int* in_sizes, int n_in,
                              void* d_out, int out_size, void* d_ws, size_t ws_size,
                              hipStream_t stream) {
  const float* x    = (const float*)d_in[0];
  const float* Wf   = (const float*)d_in[1];
  const float* bf_  = (const float*)d_in[2];
  const float* Wi   = (const float*)d_in[3];
  const float* bi_  = (const float*)d_in[4];
  const float* Wc   = (const float*)d_in[5];
  const float* bc_  = (const float*)d_in[6];
  const float* Wo   = (const float*)d_in[7];
  const float* bo_  = (const float*)d_in[8];
  const float* Wout = (const float*)d_in[9];
  const float* bout = (const float*)d_in[10];

  u16* Wint  = (u16*)((char*)d_ws + WINT_OFF);
  u32* w0b   = (u32*)((char*)d_ws + W0B_OFF);
  int* flags = (int*)((char*)d_ws + FLAG_OFF);
  u16* pub   = (u16*)((char*)d_ws + PUB_OFF);

  lstm_prep<<<1024, 256, 0, stream>>>(Wf, Wi, Wc, Wo, bf_, bi_, bc_, bo_, Wint, w0b);
  lstm_zero<<<1072, 256, 0, stream>>>((uint4*)pub, (uint4*)flags, (float*)d_out, bout);
  lstm_main<<<256, 512, 0, stream>>>(Wint, w0b, x, Wout, (float*)d_out, pub, flags);
}